// Round 4
// baseline (441.717 us; speedup 1.0000x reference)
//
#include <hip/hip_runtime.h>
#include <hip/hip_cooperative_groups.h>

namespace cg = cooperative_groups;

#define Hh 512
#define Ww 512
#define NPIX (Hh*Ww)
#define BATCH 4

__device__ __forceinline__ unsigned fkey(float f) {
    unsigned u = __float_as_uint(f);
    return (u & 0x80000000u) ? ~u : (u | 0x80000000u);
}
__device__ __forceinline__ float funkey(unsigned k) {
    unsigned u = (k & 0x80000000u) ? (k & 0x7FFFFFFFu) : ~k;
    return __uint_as_float(u);
}

// Fallback-path histogram (only used if cooperative launch is unavailable).
__global__ __launch_bounds__(256) void k_hist(const float* __restrict__ in,
                                              unsigned* __restrict__ hist) {
    __shared__ unsigned lh[64];
    const int tid = threadIdx.x;
    if (tid < 64) lh[tid] = 0u;
    __syncthreads();
    const int img = blockIdx.x >> 7, chunk = blockIdx.x & 127;
    const float4* Lp = (const float4*)(in + (size_t)img * 3 * NPIX) + chunk * 512;
    #pragma unroll
    for (int t = 0; t < 2; ++t) {
        float4 v = Lp[t*256 + tid];
        float f[4] = {v.x, v.y, v.z, v.w};
        #pragma unroll
        for (int j = 0; j < 4; ++j) {
            float ln = fminf(fmaxf(f[j] / 100.0f, 0.0f), 1.0f);
            int idx = min((int)(ln * 64.0f), 63);
            atomicAdd(&lh[idx], 1u);
        }
    }
    __syncthreads();
    if (tid < 64) atomicAdd(&hist[img*64 + tid], lh[tid]);
}

// Tile 16 wide x 32 tall; block 16x16; 2 output rows/thread.
// Staged: 46 rows x 32 cols at (by-7, bx-8). Packed-bin row stride 48B.
// FUSED=1: cooperative — in-kernel histogram + grid syncs + fused normalize.
// FUSED=0: expects hist precomputed; writes S to Sbuf for k_norm4.
template<int FUSED>
__global__ __launch_bounds__(256, 8) void k_fused(const float* __restrict__ in,
        unsigned* __restrict__ hist, unsigned* __restrict__ kmin,
        unsigned* __restrict__ kmax, float* __restrict__ Sbuf, float* __restrict__ out)
{
    __shared__ unsigned s_pk[46*12];
    __shared__ float s_c[46*36];
    __shared__ float s_cc[32*33];
    __shared__ float s_lnc[32*16];
    __shared__ unsigned lh[64];
    __shared__ float lhf[64];
    __shared__ float red[8];

    const int tx = threadIdx.x, ty = threadIdx.y;
    const int tid = ty*16 + tx;
    const int bx = blockIdx.x * 16, by = blockIdx.y * 32;
    const int img = blockIdx.z;
    const float* Lp = in + (size_t)img * 3 * NPIX;

    // ---- per-thread window byte masks (5 dwords, high bit per window byte) ----
    const int s = tx + 1;
    const int j0 = s >> 2;
    const unsigned m20 = 0x7FFFu << (s & 3);
    unsigned wm[5];
    #pragma unroll
    for (int i = 0; i < 5; ++i) {
        unsigned n = (m20 >> (4*i)) & 0xFu;
        wm[i] = (n&1u)*0x80u | (n&2u)*0x4000u | (n&4u)*0x200000u | (n&8u)*0x10000000u;
    }

    if (FUSED && tid < 64) lh[tid] = 0u;

    // ---- stage 46x32 (quad-granular bounds: quads fully in or out) ----
    for (int l = tid; l < 368; l += 256) {
        const int r = l >> 3, c4 = l & 7;
        const int gy = by - 7 + r;
        const int gx0 = bx - 8 + c4*4;
        unsigned pk = 0x7F7F7F7Fu;
        float4 cv = {0.f, 0.f, 0.f, 0.f};
        if (gy >= 0 && gy < Hh && gx0 >= 0 && gx0 < Ww) {
            const int g = gy*Ww + gx0;
            const float4 Lv = *(const float4*)(Lp + g);
            const float4 Av = *(const float4*)(Lp + NPIX + g);
            const float4 Bv = *(const float4*)(Lp + 2*NPIX + g);
            const float l0 = fminf(fmaxf(Lv.x / 100.0f, 0.0f), 1.0f);
            const float l1 = fminf(fmaxf(Lv.y / 100.0f, 0.0f), 1.0f);
            const float l2 = fminf(fmaxf(Lv.z / 100.0f, 0.0f), 1.0f);
            const float l3 = fminf(fmaxf(Lv.w / 100.0f, 0.0f), 1.0f);
            const int b0 = min((int)(l0*64.0f), 63), b1 = min((int)(l1*64.0f), 63);
            const int b2 = min((int)(l2*64.0f), 63), b3 = min((int)(l3*64.0f), 63);
            pk = (unsigned)b0 | ((unsigned)b1<<8) | ((unsigned)b2<<16) | ((unsigned)b3<<24);
            const float k255 = 1.0f/255.0f;
            cv.x = (Av.x+128.0f)*k255 + (Bv.x+128.0f)*k255;
            cv.y = (Av.y+128.0f)*k255 + (Bv.y+128.0f)*k255;
            cv.z = (Av.z+128.0f)*k255 + (Bv.z+128.0f)*k255;
            cv.w = (Av.w+128.0f)*k255 + (Bv.w+128.0f)*k255;
            if (r >= 7 && r < 39 && c4 >= 2 && c4 <= 5) {
                float4 lv4 = {l0, l1, l2, l3};
                *(float4*)&s_lnc[(r-7)*16 + 4*(c4-2)] = lv4;
            }
        }
        s_pk[r*12 + c4] = pk;
        *(float4*)&s_c[r*36 + c4*4] = cv;
    }
    for (int l = tid; l < 184; l += 256) s_pk[(l>>2)*12 + 8 + (l&3)] = 0u;
    __syncthreads();

    // ---- vertical chroma 15-sums, paired output rows ----
    for (int l = tid; l < 512; l += 256) {
        const int q = l >> 5, c = l & 31;
        float mid = 0.f;
        #pragma unroll
        for (int k = 1; k < 15; ++k) mid += s_c[(2*q+k)*36 + c];
        s_cc[(2*q)*33 + c]   = mid + s_c[(2*q)*36 + c];
        s_cc[(2*q+1)*33 + c] = mid + s_c[(2*q+15)*36 + c];
    }

    // ---- center bins (also feed in-kernel histogram when FUSED) ----
    const int r0 = 2*ty;
    const int cbyte = tx + 8;
    const unsigned cb0 = (s_pk[(r0+7)*12 + (cbyte>>2)] >> (8*(cbyte&3))) & 0xFFu;
    const unsigned cb1 = (s_pk[(r0+8)*12 + (cbyte>>2)] >> (8*(cbyte&3))) & 0xFFu;
    if (FUSED) { atomicAdd(&lh[cb0], 1u); atomicAdd(&lh[cb1], 1u); }
    __syncthreads();   // covers s_cc and lh

    if (FUSED) {
        if (tid < 64) atomicAdd(&hist[img*64 + tid], lh[tid]);
        cg::this_grid().sync();
    }
    if (tid < 64) lhf[tid] = (float)hist[img*64 + tid] * (1.0f/262144.0f);
    __syncthreads();

    // ---- own-bin match count: 5 dwords/row, 2 centers ----
    const unsigned cb40 = cb0 * 0x01010101u;
    const unsigned cb41 = cb1 * 0x01010101u;
    const unsigned K = 0x7F7F7F7Fu;
    int c0 = 0, c1 = 0;
    const unsigned* rp = s_pk + r0*12 + j0;

    { // k = 0: center0 only
        unsigned d0=rp[0], d1=rp[1], d2=rp[2], d3=rp[3], d4=rp[4];
        c0 += __popc(~((d0^cb40)+K) & wm[0]);
        c0 += __popc(~((d1^cb40)+K) & wm[1]);
        c0 += __popc(~((d2^cb40)+K) & wm[2]);
        c0 += __popc(~((d3^cb40)+K) & wm[3]);
        c0 += __popc(~((d4^cb40)+K) & wm[4]);
    }
    #pragma unroll 2
    for (int k = 1; k < 15; ++k) { // both centers
        const unsigned* rk = rp + k*12;
        unsigned d0=rk[0], d1=rk[1], d2=rk[2], d3=rk[3], d4=rk[4];
        c0 += __popc(~((d0^cb40)+K) & wm[0]);
        c1 += __popc(~((d0^cb41)+K) & wm[0]);
        c0 += __popc(~((d1^cb40)+K) & wm[1]);
        c1 += __popc(~((d1^cb41)+K) & wm[1]);
        c0 += __popc(~((d2^cb40)+K) & wm[2]);
        c1 += __popc(~((d2^cb41)+K) & wm[2]);
        c0 += __popc(~((d3^cb40)+K) & wm[3]);
        c1 += __popc(~((d3^cb41)+K) & wm[3]);
        c0 += __popc(~((d4^cb40)+K) & wm[4]);
        c1 += __popc(~((d4^cb41)+K) & wm[4]);
    }
    { // k = 15: center1 only
        const unsigned* rk = rp + 180;
        unsigned d0=rk[0], d1=rk[1], d2=rk[2], d3=rk[3], d4=rk[4];
        c1 += __popc(~((d0^cb41)+K) & wm[0]);
        c1 += __popc(~((d1^cb41)+K) & wm[1]);
        c1 += __popc(~((d2^cb41)+K) & wm[2]);
        c1 += __popc(~((d3^cb41)+K) & wm[3]);
        c1 += __popc(~((d4^cb41)+K) & wm[4]);
    }

    // ---- horizontal chroma sums ----
    float sc0 = 0.f, sc1 = 0.f;
    const float* ccp = s_cc + r0*33 + s;
    #pragma unroll
    for (int dx = 0; dx < 15; ++dx) { sc0 += ccp[dx]; sc1 += ccp[33+dx]; }

    // ---- epilogue: S, L_perp ----
    const int gx = bx + tx;
    const int gy0 = by + r0;
    const int cols  = min(gx+7, Ww-1) - max(gx-7, 0) + 1;
    const int rows0 = min(gy0+7, Hh-1) - max(gy0-7, 0) + 1;
    const int rows1 = min(gy0+8, Hh-1) - max(gy0-6, 0) + 1;
    const float inv0 = __builtin_amdgcn_rcpf((float)(rows0*cols));
    const float inv1 = __builtin_amdgcn_rcpf((float)(rows1*cols));
    const float pg0 = lhf[cb0];
    const float pg1 = lhf[cb1];
    const float S0 = -__logf(0.9f*((float)c0*inv0) + 0.1f*pg0 + 1e-6f);
    const float S1 = -__logf(0.9f*((float)c1*inv1) + 0.1f*pg1 + 1e-6f);
    const int gbase = img*NPIX + gy0*Ww + gx;

    const float lp0 = s_lnc[r0*16 + tx]     - 0.5f*(s_c[(r0+7)*36 + tx+8] - sc0*inv0);
    const float lp1 = s_lnc[(r0+1)*16 + tx] - 0.5f*(s_c[(r0+8)*36 + tx+8] - sc1*inv1);
    out[gbase]      = fminf(fmaxf(lp0, 0.f), 1.f);
    out[gbase + Ww] = fminf(fmaxf(lp1, 0.f), 1.f);

    if (!FUSED) {
        Sbuf[gbase]      = S0;
        Sbuf[gbase + Ww] = S1;
    }

    // ---- block min/max of S (min stored as max of ~fkey: zero-init works) ----
    float smin = fminf(S0, S1), smax = fmaxf(S0, S1);
    #pragma unroll
    for (int off = 32; off >= 1; off >>= 1) {
        smin = fminf(smin, __shfl_xor(smin, off));
        smax = fmaxf(smax, __shfl_xor(smax, off));
    }
    const int wid = tid >> 6;
    if ((tid & 63) == 0) { red[wid] = smin; red[4+wid] = smax; }
    __syncthreads();
    if (tid == 0) {
        float m0 = fminf(fminf(red[0],red[1]), fminf(red[2],red[3]));
        float m1 = fmaxf(fmaxf(red[4],red[5]), fmaxf(red[6],red[7]));
        atomicMax(&kmin[img], ~fkey(m0));
        atomicMax(&kmax[img],  fkey(m1));
    }

    if (FUSED) {
        cg::this_grid().sync();
        const float vmax = funkey(kmax[img]);
        const float vmin = funkey(~kmin[img]);
        const float inv = 1.0f / (vmax - vmin + 1e-6f);
        float* outN = out + (size_t)BATCH*NPIX;
        outN[gbase]      = (S0 - vmin) * inv;
        outN[gbase + Ww] = (S1 - vmin) * inv;
    }
}

__global__ __launch_bounds__(256) void k_norm4(const float4* __restrict__ Sbuf,
        const unsigned* __restrict__ kmin, const unsigned* __restrict__ kmax,
        float4* __restrict__ out) {
    const int i = blockIdx.x*256 + threadIdx.x;
    const int img = i >> 16;                       // 65536 float4 per image
    const float vmin = funkey(~kmin[img]);
    const float vmax = funkey(kmax[img]);
    const float inv = 1.0f / (vmax - vmin + 1e-6f);
    float4 S = Sbuf[i];
    float4 r;
    r.x = (S.x - vmin) * inv; r.y = (S.y - vmin) * inv;
    r.z = (S.z - vmin) * inv; r.w = (S.w - vmin) * inv;
    out[i] = r;
}

extern "C" void kernel_launch(void* const* d_in, const int* in_sizes, int n_in,
                              void* d_out, int out_size, void* d_ws, size_t ws_size,
                              hipStream_t stream) {
    const float* in = (const float*)d_in[0];
    float* out = (float*)d_out;
    unsigned* hist = (unsigned*)d_ws;                 // 1024 B
    unsigned* kmax = hist + 256;                      // 16 B @ 1024
    unsigned* kmin = hist + 260;                      // 16 B @ 1040
    float* Sbuf = (float*)((char*)d_ws + 4096);

    // hist = 0, kmax keys = 0, kmin (negated-key max) = 0 — single memset.
    hipMemsetAsync(d_ws, 0, 1056, stream);

    dim3 grid(Ww/16, Hh/32, BATCH), blk(16, 16, 1);
    const float* a0 = in; unsigned* a1 = hist; unsigned* a2 = kmin;
    unsigned* a3 = kmax; float* a4 = Sbuf; float* a5 = out;
    void* args[6] = {&a0, &a1, &a2, &a3, &a4, &a5};
    hipError_t e = hipLaunchCooperativeKernel(k_fused<1>, grid, blk, args, 0u, stream);
    if (e != hipSuccess) {
        // Fallback: non-cooperative 3-kernel pipeline (same results).
        k_hist<<<BATCH*128, 256, 0, stream>>>(in, hist);
        k_fused<0><<<grid, blk, 0, stream>>>(in, hist, kmin, kmax, Sbuf, out);
        k_norm4<<<(BATCH*NPIX/4)/256, 256, 0, stream>>>((const float4*)Sbuf, kmin, kmax,
                                                        (float4*)(out + (size_t)BATCH*NPIX));
    }
}

// Round 5
// 84.849 us; speedup vs baseline: 5.2059x; 5.2059x over previous
//
#include <hip/hip_runtime.h>

#define Hh 512
#define Ww 512
#define NPIX (Hh*Ww)
#define BATCH 4

// ws layout (no initialization required anywhere):
//   bmin: float[4][512]      @ 0      (8 KB)   per-block S min (plain stores)
//   bmax: float[4][512]      @ 8192   (8 KB)   per-block S max
//   hp:   uint [4][64][64]   @ 16384  (64 KB)  per-block partial histograms

__global__ __launch_bounds__(256) void k_hist(const float* __restrict__ in,
                                              unsigned* __restrict__ hp) {
    __shared__ unsigned lh[64];
    const int tid = threadIdx.x;
    if (tid < 64) lh[tid] = 0u;
    __syncthreads();
    const int img = blockIdx.x >> 6, sub = blockIdx.x & 63;
    const float4* Lp = (const float4*)(in + (size_t)img * 3 * NPIX) + sub * 1024;
    #pragma unroll
    for (int t = 0; t < 4; ++t) {
        float4 v = Lp[t*256 + tid];
        float f[4] = {v.x, v.y, v.z, v.w};
        #pragma unroll
        for (int j = 0; j < 4; ++j) {
            float ln = fminf(fmaxf(f[j] / 100.0f, 0.0f), 1.0f);
            int idx = min((int)(ln * 64.0f), 63);
            atomicAdd(&lh[idx], 1u);
        }
    }
    __syncthreads();
    if (tid < 64) hp[(img*64 + sub)*64 + tid] = lh[tid];   // plain store
}

// Tile 16 wide x 32 tall; block 16x16; 2 output rows/thread.
// Staged: 46 rows x 32 cols at (by-7, bx-8). Packed-bin row stride 48B.
__global__ __launch_bounds__(256, 8) void k_main(const float* __restrict__ in,
        const unsigned* __restrict__ hp, float* __restrict__ bmin,
        float* __restrict__ bmax, float* __restrict__ out)
{
    __shared__ unsigned s_pk[46*12];
    __shared__ float s_c[46*36];
    __shared__ float s_cc[32*33];
    __shared__ float s_lnc[32*16];
    __shared__ float lhf[64];
    __shared__ float red[8];

    const int tx = threadIdx.x, ty = threadIdx.y;
    const int tid = ty*16 + tx;
    const int bx = blockIdx.x * 16, by = blockIdx.y * 32;
    const int img = blockIdx.z;
    const float* Lp = in + (size_t)img * 3 * NPIX;

    // ---- phase 0: reduce per-image partial hist (wave 0, overlaps staging) ----
    if (tid < 64) {
        unsigned sum = 0;
        const unsigned* p = hp + img*4096 + tid;
        #pragma unroll 8
        for (int q = 0; q < 64; ++q) sum += p[q*64];
        lhf[tid] = (float)sum * (1.0f/262144.0f);
    }

    // ---- per-thread window byte masks (5 dwords, high bit per window byte) ----
    const int s = tx + 1;
    const int j0 = s >> 2;
    const unsigned m20 = 0x7FFFu << (s & 3);
    unsigned wm[5];
    #pragma unroll
    for (int i = 0; i < 5; ++i) {
        unsigned n = (m20 >> (4*i)) & 0xFu;
        wm[i] = (n&1u)*0x80u | (n&2u)*0x4000u | (n&4u)*0x200000u | (n&8u)*0x10000000u;
    }

    // ---- stage 46x32 (quad-granular bounds: quads fully in or out) ----
    for (int l = tid; l < 368; l += 256) {
        const int r = l >> 3, c4 = l & 7;
        const int gy = by - 7 + r;
        const int gx0 = bx - 8 + c4*4;
        unsigned pk = 0x7F7F7F7Fu;
        float4 cv = {0.f, 0.f, 0.f, 0.f};
        if (gy >= 0 && gy < Hh && gx0 >= 0 && gx0 < Ww) {
            const int g = gy*Ww + gx0;
            const float4 Lv = *(const float4*)(Lp + g);
            const float4 Av = *(const float4*)(Lp + NPIX + g);
            const float4 Bv = *(const float4*)(Lp + 2*NPIX + g);
            const float l0 = fminf(fmaxf(Lv.x / 100.0f, 0.0f), 1.0f);
            const float l1 = fminf(fmaxf(Lv.y / 100.0f, 0.0f), 1.0f);
            const float l2 = fminf(fmaxf(Lv.z / 100.0f, 0.0f), 1.0f);
            const float l3 = fminf(fmaxf(Lv.w / 100.0f, 0.0f), 1.0f);
            const int b0 = min((int)(l0*64.0f), 63), b1 = min((int)(l1*64.0f), 63);
            const int b2 = min((int)(l2*64.0f), 63), b3 = min((int)(l3*64.0f), 63);
            pk = (unsigned)b0 | ((unsigned)b1<<8) | ((unsigned)b2<<16) | ((unsigned)b3<<24);
            const float k255 = 1.0f/255.0f;
            cv.x = (Av.x+128.0f)*k255 + (Bv.x+128.0f)*k255;
            cv.y = (Av.y+128.0f)*k255 + (Bv.y+128.0f)*k255;
            cv.z = (Av.z+128.0f)*k255 + (Bv.z+128.0f)*k255;
            cv.w = (Av.w+128.0f)*k255 + (Bv.w+128.0f)*k255;
            if (r >= 7 && r < 39 && c4 >= 2 && c4 <= 5) {
                float4 lv4 = {l0, l1, l2, l3};
                *(float4*)&s_lnc[(r-7)*16 + 4*(c4-2)] = lv4;
            }
        }
        s_pk[r*12 + c4] = pk;
        *(float4*)&s_c[r*36 + c4*4] = cv;
    }
    for (int l = tid; l < 184; l += 256) s_pk[(l>>2)*12 + 8 + (l&3)] = 0u;
    __syncthreads();

    // ---- vertical chroma 15-sums, paired output rows ----
    for (int l = tid; l < 512; l += 256) {
        const int q = l >> 5, c = l & 31;
        float mid = 0.f;
        #pragma unroll
        for (int k = 1; k < 15; ++k) mid += s_c[(2*q+k)*36 + c];
        s_cc[(2*q)*33 + c]   = mid + s_c[(2*q)*36 + c];
        s_cc[(2*q+1)*33 + c] = mid + s_c[(2*q+15)*36 + c];
    }
    __syncthreads();

    // ---- own-bin match count: 5 dwords/row, 2 centers ----
    const int r0 = 2*ty;
    const int cbyte = tx + 8;
    const unsigned cb0 = (s_pk[(r0+7)*12 + (cbyte>>2)] >> (8*(cbyte&3))) & 0xFFu;
    const unsigned cb1 = (s_pk[(r0+8)*12 + (cbyte>>2)] >> (8*(cbyte&3))) & 0xFFu;
    const unsigned cb40 = cb0 * 0x01010101u;
    const unsigned cb41 = cb1 * 0x01010101u;
    const unsigned K = 0x7F7F7F7Fu;
    int c0 = 0, c1 = 0;
    const unsigned* rp = s_pk + r0*12 + j0;

    { // k = 0: center0 only
        unsigned d0=rp[0], d1=rp[1], d2=rp[2], d3=rp[3], d4=rp[4];
        c0 += __popc(~((d0^cb40)+K) & wm[0]);
        c0 += __popc(~((d1^cb40)+K) & wm[1]);
        c0 += __popc(~((d2^cb40)+K) & wm[2]);
        c0 += __popc(~((d3^cb40)+K) & wm[3]);
        c0 += __popc(~((d4^cb40)+K) & wm[4]);
    }
    #pragma unroll 2
    for (int k = 1; k < 15; ++k) { // both centers
        const unsigned* rk = rp + k*12;
        unsigned d0=rk[0], d1=rk[1], d2=rk[2], d3=rk[3], d4=rk[4];
        c0 += __popc(~((d0^cb40)+K) & wm[0]);
        c1 += __popc(~((d0^cb41)+K) & wm[0]);
        c0 += __popc(~((d1^cb40)+K) & wm[1]);
        c1 += __popc(~((d1^cb41)+K) & wm[1]);
        c0 += __popc(~((d2^cb40)+K) & wm[2]);
        c1 += __popc(~((d2^cb41)+K) & wm[2]);
        c0 += __popc(~((d3^cb40)+K) & wm[3]);
        c1 += __popc(~((d3^cb41)+K) & wm[3]);
        c0 += __popc(~((d4^cb40)+K) & wm[4]);
        c1 += __popc(~((d4^cb41)+K) & wm[4]);
    }
    { // k = 15: center1 only
        const unsigned* rk = rp + 180;
        unsigned d0=rk[0], d1=rk[1], d2=rk[2], d3=rk[3], d4=rk[4];
        c1 += __popc(~((d0^cb41)+K) & wm[0]);
        c1 += __popc(~((d1^cb41)+K) & wm[1]);
        c1 += __popc(~((d2^cb41)+K) & wm[2]);
        c1 += __popc(~((d3^cb41)+K) & wm[3]);
        c1 += __popc(~((d4^cb41)+K) & wm[4]);
    }

    // ---- horizontal chroma sums ----
    float sc0 = 0.f, sc1 = 0.f;
    const float* ccp = s_cc + r0*33 + s;
    #pragma unroll
    for (int dx = 0; dx < 15; ++dx) { sc0 += ccp[dx]; sc1 += ccp[33+dx]; }

    // ---- epilogue: S (to out second half), L_perp ----
    const int gx = bx + tx;
    const int gy0 = by + r0;
    const int cols  = min(gx+7, Ww-1) - max(gx-7, 0) + 1;
    const int rows0 = min(gy0+7, Hh-1) - max(gy0-7, 0) + 1;
    const int rows1 = min(gy0+8, Hh-1) - max(gy0-6, 0) + 1;
    const float inv0 = __builtin_amdgcn_rcpf((float)(rows0*cols));
    const float inv1 = __builtin_amdgcn_rcpf((float)(rows1*cols));
    const float pg0 = lhf[cb0];
    const float pg1 = lhf[cb1];
    const float S0 = -__logf(0.9f*((float)c0*inv0) + 0.1f*pg0 + 1e-6f);
    const float S1 = -__logf(0.9f*((float)c1*inv1) + 0.1f*pg1 + 1e-6f);
    const int gbase = img*NPIX + gy0*Ww + gx;

    const float lp0 = s_lnc[r0*16 + tx]     - 0.5f*(s_c[(r0+7)*36 + tx+8] - sc0*inv0);
    const float lp1 = s_lnc[(r0+1)*16 + tx] - 0.5f*(s_c[(r0+8)*36 + tx+8] - sc1*inv1);
    out[gbase]      = fminf(fmaxf(lp0, 0.f), 1.f);
    out[gbase + Ww] = fminf(fmaxf(lp1, 0.f), 1.f);
    float* outN = out + (size_t)BATCH*NPIX;
    outN[gbase]      = S0;     // unnormalized S; k_norm normalizes in place
    outN[gbase + Ww] = S1;

    // ---- block min/max of S -> plain per-block stores (no atomics/init) ----
    float smin = fminf(S0, S1), smax = fmaxf(S0, S1);
    #pragma unroll
    for (int off = 32; off >= 1; off >>= 1) {
        smin = fminf(smin, __shfl_xor(smin, off));
        smax = fmaxf(smax, __shfl_xor(smax, off));
    }
    const int wid = tid >> 6;
    if ((tid & 63) == 0) { red[wid] = smin; red[4+wid] = smax; }
    __syncthreads();
    if (tid == 0) {
        const int bid = blockIdx.y*32 + blockIdx.x;   // 512 blocks/image
        bmin[img*512 + bid] = fminf(fminf(red[0],red[1]), fminf(red[2],red[3]));
        bmax[img*512 + bid] = fmaxf(fmaxf(red[4],red[5]), fmaxf(red[6],red[7]));
    }
}

// In-place normalize of outN. 1024 blocks x 256 threads; 1 float4/thread.
__global__ __launch_bounds__(256) void k_norm(float* __restrict__ outN,
        const float* __restrict__ bmin, const float* __restrict__ bmax) {
    __shared__ float red[8];
    const int tid = threadIdx.x;
    const int img = blockIdx.x >> 8;

    float mn = __builtin_inff(), mx = -__builtin_inff();
    if (tid < 128) {
        float4 a = ((const float4*)(bmin + img*512))[tid];
        float4 b = ((const float4*)(bmax + img*512))[tid];
        mn = fminf(fminf(a.x, a.y), fminf(a.z, a.w));
        mx = fmaxf(fmaxf(b.x, b.y), fmaxf(b.z, b.w));
    }
    #pragma unroll
    for (int off = 32; off >= 1; off >>= 1) {
        mn = fminf(mn, __shfl_xor(mn, off));
        mx = fmaxf(mx, __shfl_xor(mx, off));
    }
    if ((tid & 63) == 0) { red[tid>>6] = mn; red[4 + (tid>>6)] = mx; }
    __syncthreads();
    const float vmin = fminf(fminf(red[0],red[1]), fminf(red[2],red[3]));
    const float vmax = fmaxf(fmaxf(red[4],red[5]), fmaxf(red[6],red[7]));
    const float inv = 1.0f / (vmax - vmin + 1e-6f);

    float4* p = (float4*)outN + (size_t)blockIdx.x*256;
    float4 v = p[tid];
    v.x = (v.x - vmin) * inv; v.y = (v.y - vmin) * inv;
    v.z = (v.z - vmin) * inv; v.w = (v.w - vmin) * inv;
    p[tid] = v;
}

extern "C" void kernel_launch(void* const* d_in, const int* in_sizes, int n_in,
                              void* d_out, int out_size, void* d_ws, size_t ws_size,
                              hipStream_t stream) {
    const float* in = (const float*)d_in[0];
    float* out = (float*)d_out;
    float* bmin = (float*)d_ws;                          // 8 KB
    float* bmax = bmin + BATCH*512;                      // 8 KB
    unsigned* hp = (unsigned*)(bmax + BATCH*512);        // 64 KB

    k_hist<<<BATCH*64, 256, 0, stream>>>(in, hp);
    dim3 grid(Ww/16, Hh/32, BATCH), blk(16, 16);
    k_main<<<grid, blk, 0, stream>>>(in, hp, bmin, bmax, out);
    k_norm<<<BATCH*256, 256, 0, stream>>>(out + (size_t)BATCH*NPIX, bmin, bmax);
}

// Round 6
// 83.942 us; speedup vs baseline: 5.2622x; 1.0108x over previous
//
#include <hip/hip_runtime.h>

#define Hh 512
#define Ww 512
#define NPIX (Hh*Ww)
#define BATCH 4

// ws layout (no initialization required anywhere):
//   bmin: float[4][512]        @ 0      (8 KB)  per-block S min (plain stores)
//   bmax: float[4][512]        @ 8192   (8 KB)  per-block S max
//   hp:   uint [4][64bin][64s] @ 16384  (64 KB) per-block partial histograms (transposed)

__global__ __launch_bounds__(256) void k_hist(const float* __restrict__ in,
                                              unsigned* __restrict__ hp) {
    __shared__ unsigned lh[64];
    const int tid = threadIdx.x;
    if (tid < 64) lh[tid] = 0u;
    __syncthreads();
    const int img = blockIdx.x >> 6, sub = blockIdx.x & 63;
    const float4* Lp = (const float4*)(in + (size_t)img * 3 * NPIX) + sub * 1024;
    #pragma unroll
    for (int t = 0; t < 4; ++t) {
        float4 v = Lp[t*256 + tid];
        float f[4] = {v.x, v.y, v.z, v.w};
        #pragma unroll
        for (int j = 0; j < 4; ++j) {
            float ln = fminf(fmaxf(f[j] / 100.0f, 0.0f), 1.0f);
            int idx = min((int)(ln * 64.0f), 63);
            atomicAdd(&lh[idx], 1u);
        }
    }
    __syncthreads();
    if (tid < 64) hp[((size_t)img*64 + tid)*64 + sub] = lh[tid];   // [img][bin][sub]
}

// Tile 16 wide x 32 tall; block 16x16; 2 output rows/thread.
// Staged: 46 rows x 32 cols at (by-7, bx-8). Packed-bin row stride 9 dwords
// (dwords 0..7 = bins, dword 8 dead — reads of it are fully masked by wm).
__global__ __launch_bounds__(256, 8) void k_main(const float* __restrict__ in,
        const unsigned* __restrict__ hp, float* __restrict__ bmin,
        float* __restrict__ bmax, float* __restrict__ out)
{
    __shared__ unsigned s_pk[46*9];
    __shared__ float s_c[46*36];
    __shared__ float s_cc[32*33];
    __shared__ float s_lnc[32*16];
    __shared__ float lhf[64];
    __shared__ float red[8];

    const int tx = threadIdx.x, ty = threadIdx.y;
    const int tid = ty*16 + tx;
    const int bx = blockIdx.x * 16, by = blockIdx.y * 32;
    const int img = blockIdx.z;
    const float* Lp = in + (size_t)img * 3 * NPIX;

    // ---- phase 0: coalesced hist reduce (all 256 threads, 4 uint4 each) ----
    {
        const int bin = tid >> 2, grp = tid & 3;
        const uint4* p = (const uint4*)(hp + ((size_t)img*64 + bin)*64 + grp*16);
        uint4 x0 = p[0], x1 = p[1], x2 = p[2], x3 = p[3];
        unsigned sum = x0.x+x0.y+x0.z+x0.w + x1.x+x1.y+x1.z+x1.w
                     + x2.x+x2.y+x2.z+x2.w + x3.x+x3.y+x3.z+x3.w;
        sum += __shfl_xor(sum, 1);
        sum += __shfl_xor(sum, 2);
        if (grp == 0) lhf[bin] = (float)sum * (1.0f/262144.0f);
    }

    // ---- per-thread window byte masks (5 dwords, high bit per window byte) ----
    const int s = tx + 1;
    const int j0 = s >> 2;
    const unsigned m20 = 0x7FFFu << (s & 3);
    unsigned wm[5];
    #pragma unroll
    for (int i = 0; i < 5; ++i) {
        unsigned n = (m20 >> (4*i)) & 0xFu;
        wm[i] = (n&1u)*0x80u | (n&2u)*0x4000u | (n&4u)*0x200000u | (n&8u)*0x10000000u;
    }

    // ---- stage 46x32: prefetch ALL global loads into registers first ----
    float4 Lv[2], Av[2], Bv[2];
    bool vld[2];
    #pragma unroll
    for (int it = 0; it < 2; ++it) {
        const int l = tid + it*256;
        const int r = l >> 3, c4 = l & 7;
        const int gy = by - 7 + r, gx0 = bx - 8 + c4*4;
        vld[it] = (l < 368) && gy >= 0 && gy < Hh && gx0 >= 0 && gx0 < Ww;
        if (vld[it]) {
            const int g = gy*Ww + gx0;
            Lv[it] = *(const float4*)(Lp + g);
            Av[it] = *(const float4*)(Lp + NPIX + g);
            Bv[it] = *(const float4*)(Lp + 2*NPIX + g);
        }
    }
    #pragma unroll
    for (int it = 0; it < 2; ++it) {
        const int l = tid + it*256;
        if (l < 368) {
            const int r = l >> 3, c4 = l & 7;
            unsigned pk = 0x7F7F7F7Fu;
            float4 cv = {0.f, 0.f, 0.f, 0.f};
            if (vld[it]) {
                const float l0 = fminf(fmaxf(Lv[it].x / 100.0f, 0.0f), 1.0f);
                const float l1 = fminf(fmaxf(Lv[it].y / 100.0f, 0.0f), 1.0f);
                const float l2 = fminf(fmaxf(Lv[it].z / 100.0f, 0.0f), 1.0f);
                const float l3 = fminf(fmaxf(Lv[it].w / 100.0f, 0.0f), 1.0f);
                const int b0 = min((int)(l0*64.0f), 63), b1 = min((int)(l1*64.0f), 63);
                const int b2 = min((int)(l2*64.0f), 63), b3 = min((int)(l3*64.0f), 63);
                pk = (unsigned)b0 | ((unsigned)b1<<8) | ((unsigned)b2<<16) | ((unsigned)b3<<24);
                const float k255 = 1.0f/255.0f;
                cv.x = (Av[it].x+128.0f)*k255 + (Bv[it].x+128.0f)*k255;
                cv.y = (Av[it].y+128.0f)*k255 + (Bv[it].y+128.0f)*k255;
                cv.z = (Av[it].z+128.0f)*k255 + (Bv[it].z+128.0f)*k255;
                cv.w = (Av[it].w+128.0f)*k255 + (Bv[it].w+128.0f)*k255;
                if (r >= 7 && r < 39 && c4 >= 2 && c4 <= 5) {
                    float4 lv4 = {l0, l1, l2, l3};
                    *(float4*)&s_lnc[(r-7)*16 + 4*(c4-2)] = lv4;
                }
            }
            s_pk[r*9 + c4] = pk;
            *(float4*)&s_c[r*36 + c4*4] = cv;
        }
    }
    __syncthreads();

    // ---- vertical chroma 15-sums, paired output rows ----
    for (int l = tid; l < 512; l += 256) {
        const int q = l >> 5, c = l & 31;
        float mid = 0.f;
        #pragma unroll
        for (int k = 1; k < 15; ++k) mid += s_c[(2*q+k)*36 + c];
        s_cc[(2*q)*33 + c]   = mid + s_c[(2*q)*36 + c];
        s_cc[(2*q+1)*33 + c] = mid + s_c[(2*q+15)*36 + c];
    }
    __syncthreads();

    // ---- own-bin match count: fully unrolled, 4 independent chains ----
    const int r0 = 2*ty;
    const int cbyte = tx + 8;
    const unsigned cb0 = (s_pk[(r0+7)*9 + (cbyte>>2)] >> (8*(cbyte&3))) & 0xFFu;
    const unsigned cb1 = (s_pk[(r0+8)*9 + (cbyte>>2)] >> (8*(cbyte&3))) & 0xFFu;
    const unsigned cb40 = cb0 * 0x01010101u;
    const unsigned cb41 = cb1 * 0x01010101u;
    const unsigned K = 0x7F7F7F7Fu;
    int a0 = 0, a1 = 0, a2 = 0, a3 = 0;
    const unsigned* rp = s_pk + r0*9 + j0;

    #pragma unroll
    for (int k = 0; k < 16; ++k) {
        const unsigned d0 = rp[k*9+0], d1 = rp[k*9+1], d2 = rp[k*9+2],
                       d3 = rp[k*9+3], d4 = rp[k*9+4];
        if (k != 15) {
            a0 += __popc(~((d0^cb40)+K) & wm[0]);
            a1 += __popc(~((d1^cb40)+K) & wm[1]);
            a0 += __popc(~((d2^cb40)+K) & wm[2]);
            a1 += __popc(~((d3^cb40)+K) & wm[3]);
            a0 += __popc(~((d4^cb40)+K) & wm[4]);
        }
        if (k != 0) {
            a2 += __popc(~((d0^cb41)+K) & wm[0]);
            a3 += __popc(~((d1^cb41)+K) & wm[1]);
            a2 += __popc(~((d2^cb41)+K) & wm[2]);
            a3 += __popc(~((d3^cb41)+K) & wm[3]);
            a2 += __popc(~((d4^cb41)+K) & wm[4]);
        }
    }
    const int c0 = a0 + a1, c1 = a2 + a3;

    // ---- horizontal chroma sums ----
    float sc0 = 0.f, sc1 = 0.f;
    const float* ccp = s_cc + r0*33 + s;
    #pragma unroll
    for (int dx = 0; dx < 15; ++dx) { sc0 += ccp[dx]; sc1 += ccp[33+dx]; }

    // ---- epilogue: S (to out second half), L_perp ----
    const int gx = bx + tx;
    const int gy0 = by + r0;
    const int cols  = min(gx+7, Ww-1) - max(gx-7, 0) + 1;
    const int rows0 = min(gy0+7, Hh-1) - max(gy0-7, 0) + 1;
    const int rows1 = min(gy0+8, Hh-1) - max(gy0-6, 0) + 1;
    const float inv0 = __builtin_amdgcn_rcpf((float)(rows0*cols));
    const float inv1 = __builtin_amdgcn_rcpf((float)(rows1*cols));
    const float pg0 = lhf[cb0];
    const float pg1 = lhf[cb1];
    const float S0 = -__logf(0.9f*((float)c0*inv0) + 0.1f*pg0 + 1e-6f);
    const float S1 = -__logf(0.9f*((float)c1*inv1) + 0.1f*pg1 + 1e-6f);
    const int gbase = img*NPIX + gy0*Ww + gx;

    const float lp0 = s_lnc[r0*16 + tx]     - 0.5f*(s_c[(r0+7)*36 + tx+8] - sc0*inv0);
    const float lp1 = s_lnc[(r0+1)*16 + tx] - 0.5f*(s_c[(r0+8)*36 + tx+8] - sc1*inv1);
    out[gbase]      = fminf(fmaxf(lp0, 0.f), 1.f);
    out[gbase + Ww] = fminf(fmaxf(lp1, 0.f), 1.f);
    float* outN = out + (size_t)BATCH*NPIX;
    outN[gbase]      = S0;     // unnormalized S; k_norm normalizes in place
    outN[gbase + Ww] = S1;

    // ---- block min/max of S -> plain per-block stores (no atomics/init) ----
    float smin = fminf(S0, S1), smax = fmaxf(S0, S1);
    #pragma unroll
    for (int off = 32; off >= 1; off >>= 1) {
        smin = fminf(smin, __shfl_xor(smin, off));
        smax = fmaxf(smax, __shfl_xor(smax, off));
    }
    const int wid = tid >> 6;
    if ((tid & 63) == 0) { red[wid] = smin; red[4+wid] = smax; }
    __syncthreads();
    if (tid == 0) {
        const int bid = blockIdx.y*32 + blockIdx.x;   // 512 blocks/image
        bmin[img*512 + bid] = fminf(fminf(red[0],red[1]), fminf(red[2],red[3]));
        bmax[img*512 + bid] = fmaxf(fmaxf(red[4],red[5]), fmaxf(red[6],red[7]));
    }
}

// In-place normalize of outN. 1024 blocks x 256 threads; 1 float4/thread.
__global__ __launch_bounds__(256) void k_norm(float* __restrict__ outN,
        const float* __restrict__ bmin, const float* __restrict__ bmax) {
    __shared__ float red[8];
    const int tid = threadIdx.x;
    const int img = blockIdx.x >> 8;

    float mn = __builtin_inff(), mx = -__builtin_inff();
    if (tid < 128) {
        float4 a = ((const float4*)(bmin + img*512))[tid];
        float4 b = ((const float4*)(bmax + img*512))[tid];
        mn = fminf(fminf(a.x, a.y), fminf(a.z, a.w));
        mx = fmaxf(fmaxf(b.x, b.y), fmaxf(b.z, b.w));
    }
    #pragma unroll
    for (int off = 32; off >= 1; off >>= 1) {
        mn = fminf(mn, __shfl_xor(mn, off));
        mx = fmaxf(mx, __shfl_xor(mx, off));
    }
    if ((tid & 63) == 0) { red[tid>>6] = mn; red[4 + (tid>>6)] = mx; }
    __syncthreads();
    const float vmin = fminf(fminf(red[0],red[1]), fminf(red[2],red[3]));
    const float vmax = fmaxf(fmaxf(red[4],red[5]), fmaxf(red[6],red[7]));
    const float inv = 1.0f / (vmax - vmin + 1e-6f);

    float4* p = (float4*)outN + (size_t)blockIdx.x*256;
    float4 v = p[tid];
    v.x = (v.x - vmin) * inv; v.y = (v.y - vmin) * inv;
    v.z = (v.z - vmin) * inv; v.w = (v.w - vmin) * inv;
    p[tid] = v;
}

extern "C" void kernel_launch(void* const* d_in, const int* in_sizes, int n_in,
                              void* d_out, int out_size, void* d_ws, size_t ws_size,
                              hipStream_t stream) {
    const float* in = (const float*)d_in[0];
    float* out = (float*)d_out;
    float* bmin = (float*)d_ws;                          // 8 KB
    float* bmax = bmin + BATCH*512;                      // 8 KB
    unsigned* hp = (unsigned*)(bmax + BATCH*512);        // 64 KB

    k_hist<<<BATCH*64, 256, 0, stream>>>(in, hp);
    dim3 grid(Ww/16, Hh/32, BATCH), blk(16, 16);
    k_main<<<grid, blk, 0, stream>>>(in, hp, bmin, bmax, out);
    k_norm<<<BATCH*256, 256, 0, stream>>>(out + (size_t)BATCH*NPIX, bmin, bmax);
}